// Round 8
// baseline (137.521 us; speedup 1.0000x reference)
//
#include <hip/hip_runtime.h>

#define Bb 8
#define Cc 64
#define Oo 64
#define Hh 96
#define Ww 96
#define HW 9216
#define NOFF 18

typedef __bf16 bf16_t;
typedef __bf16 bf16x2 __attribute__((ext_vector_type(2)));
typedef __bf16 bf16x8 __attribute__((ext_vector_type(8)));
typedef float  f32x4  __attribute__((ext_vector_type(4)));

// ws layout:
//   xt   : Bb*HW*Cc  bf16     [b][hw][c]
//   wtpd : 18*4*64*8 bf16     deform weights, A-fragment order
//   wtpo : 18*2*64*8 bf16     offset-conv weights, A-fragment order
#define XT_SZ   (Bb*HW*Cc)
#define WTPD_SZ (18*4*64*8)
#define WTPO_SZ (18*2*64*8)

// ---------------- kernel 1: x transpose + weight prepack (one grid) ----------------
__global__ void xpose_prep(const float* __restrict__ x, const float* __restrict__ cw,
                           const float* __restrict__ ow, bf16_t* __restrict__ xt,
                           bf16_t* __restrict__ wtpd, bf16_t* __restrict__ wtpo) {
    __shared__ float tile[64][65];
    int bid = blockIdx.x;
    if (bid < 1152) {
        int b    = bid / 144;
        int t0   = (bid % 144) * 64;
        int lane = threadIdx.x & 63;
        int sub  = threadIdx.x >> 6;
        const float* xb = x + (size_t)b * Cc * HW;
        #pragma unroll
        for (int i = 0; i < 16; ++i) {
            int c = sub * 16 + i;
            tile[c][lane] = xb[c * HW + t0 + lane];
        }
        __syncthreads();
        bf16_t* xtb = xt + ((size_t)b * HW + t0) * Cc;
        int half = lane >> 5, cpair = lane & 31;
        #pragma unroll
        for (int i = 0; i < 8; ++i) {
            int hw = sub * 16 + half * 8 + i;
            bf16x2 v;
            v[0] = (bf16_t)tile[cpair * 2][hw];
            v[1] = (bf16_t)tile[cpair * 2 + 1][hw];
            *(bf16x2*)&xtb[hw * Cc + cpair * 2] = v;
        }
    } else if (bid < 1170) {
        int n = (bid - 1152) * 256 + threadIdx.x;    // 0..4607
        int t = n >> 8; int rem = n & 255; int mt = rem >> 6; int l = rem & 63;
        int o = mt * 16 + (l & 15);
        int kbase = t * 32 + ((l >> 4) & 3) * 8;
        bf16x8 v;
        #pragma unroll
        for (int j = 0; j < 8; ++j) {
            int kidx = kbase + j; int k = kidx >> 6; int c = kidx & 63;
            v[j] = (bf16_t)cw[(o * 64 + c) * 9 + k];
        }
        *(bf16x8*)&wtpd[n * 8] = v;
    } else {
        int n = (bid - 1170) * 256 + threadIdx.x;    // 0..2303
        int t = n >> 7; int rem = n & 127; int mt = rem >> 6; int l = rem & 63;
        int oc = mt * 16 + (l & 15);
        int kbase = t * 32 + ((l >> 4) & 3) * 8;
        bf16x8 v;
        #pragma unroll
        for (int j = 0; j < 8; ++j) {
            int kidx = kbase + j; int k = kidx >> 6; int c = kidx & 63;
            v[j] = (oc < NOFF) ? (bf16_t)ow[(oc * 64 + c) * 9 + k] : (bf16_t)0.f;
        }
        *(bf16x8*)&wtpo[n * 8] = v;
    }
}

// ---------------- kernel 2: fused offset-conv + deformable conv ----------------
// XCD swizzle: b = bid&7 pins each XCD to one batch (L2-resident xt slice).
// 8x8 pixel tiles: per-block tap footprint ~13x13x128B = 21.6 KB < 32 KB L1,
// so bilinear corner reads hit L1 after first touch (vs 50 KB for 64x1 rows).
// Weight streams (>L1) use non-temporal loads so they don't evict gather lines.
__global__ __launch_bounds__(256, 4) void fused_dcn(const bf16_t* __restrict__ xt,
        const bf16_t* __restrict__ wtpo, const bf16_t* __restrict__ wtpd,
        const float* __restrict__ ob, const float* __restrict__ cb,
        float* __restrict__ out) {
    __shared__ float offbuf[64 * 20];            // [pix][18 pad 20]
    __shared__ bf16_t Sa[4][16 * 72];            // wave-private staging (both phases)

    int bid = blockIdx.x;
    int b = bid & 7;                              // XCD-aware remap
    int t8 = bid >> 3;                            // tile 0..143
    int h0 = (t8 / 12) * 8, w0 = (t8 % 12) * 8;   // 8x8 tile origin
    int tid = threadIdx.x, lane = tid & 63, q = tid >> 6;
    int cg = lane & 7, prow = lane >> 3;
    int cb8 = cg * 8;
    bf16_t* myS = &Sa[q][0];
    int bbase = b * HW;

    // wave q owns pixels q*16..q*16+15 = tile rows (q*2, q*2+1), cols 0..7
    int pl[2], ph[2], pw[2];
    #pragma unroll
    for (int i = 0; i < 2; ++i) {
        pl[i] = q * 16 + i * 8 + prow;            // pixel index in block
        ph[i] = h0 + q * 2 + i;                   // image row
        pw[i] = w0 + prow;                        // image col
    }

    const bf16x8* wtpo_v = (const bf16x8*)wtpo;
    const bf16x8* wtpd_v = (const bf16x8*)wtpd;

    // ---- phase 1: offset conv ----
    {
        f32x4 acc[2];
        #pragma unroll
        for (int mt = 0; mt < 2; ++mt)
            #pragma unroll
            for (int r = 0; r < 4; ++r) {
                int oc = mt * 16 + ((lane >> 4) & 3) * 4 + r;
                acc[mt][r] = (oc < NOFF) ? ob[oc] : 0.f;
            }
        bf16x8 g[2];
        auto issue = [&](int k, bf16x8 (&gg)[2]) {
            const int ky = k / 3, kx = k % 3;
            #pragma unroll
            for (int i = 0; i < 2; ++i) {
                int y = ph[i] - 1 + ky, x = pw[i] - 1 + kx;
                bool valid = (y >= 0) && (y < Hh) && (x >= 0) && (x < Ww);
                bf16x8 v;
                #pragma unroll
                for (int j = 0; j < 8; ++j) v[j] = (bf16_t)0.f;
                if (valid) v = *(const bf16x8*)(xt + ((bbase + y * Ww + x) * Cc + cb8));
                gg[i] = v;
            }
        };
        issue(0, g);
        #pragma unroll
        for (int k = 0; k < 9; ++k) {
            #pragma unroll
            for (int i = 0; i < 2; ++i)
                *(bf16x8*)&myS[(i * 8 + prow) * 72 + cb8] = g[i];   // pure bf16 copy
            if (k < 8) issue(k + 1, g);
            #pragma unroll
            for (int s = 0; s < 2; ++s) {
                bf16x8 bfrag = *(bf16x8*)&myS[(lane & 15) * 72 + s * 32 + ((lane >> 4) & 3) * 8];
                int t = k * 2 + s;
                #pragma unroll
                for (int mt = 0; mt < 2; ++mt) {
                    bf16x8 afrag = __builtin_nontemporal_load(&wtpo_v[(t * 2 + mt) * 64 + lane]);
                    acc[mt] = __builtin_amdgcn_mfma_f32_16x16x32_bf16(afrag, bfrag, acc[mt], 0, 0, 0);
                }
            }
        }
        // C-layout -> [pix][18] LDS (the transform deform needs anyway)
        #pragma unroll
        for (int mt = 0; mt < 2; ++mt)
            #pragma unroll
            for (int r = 0; r < 4; ++r) {
                int oc = mt * 16 + ((lane >> 4) & 3) * 4 + r;
                if (oc < NOFF)
                    offbuf[(q * 16 + (lane & 15)) * 20 + oc] = acc[mt][r];
            }
    }
    __syncthreads();

    // ---- phase 2: deformable conv ----
    f32x4 acc[4];
    #pragma unroll
    for (int mt = 0; mt < 4; ++mt)
        #pragma unroll
        for (int r = 0; r < 4; ++r)
            acc[mt][r] = cb[mt * 16 + ((lane >> 4) & 3) * 4 + r];

    bf16x8 g[2][4];     // in-flight gather: [i][corner], 16 B each
    float w4[2][4];     // bilinear weights (validity-premultiplied)
    auto issue = [&](int k, bf16x8 (&gg)[2][4], float (&ww)[2][4]) {
        const int ky = k / 3, kx = k % 3;
        #pragma unroll
        for (int i = 0; i < 2; ++i) {
            float2 od = *(float2*)&offbuf[pl[i] * 20 + 2 * k];
            float py = (float)(ph[i] - 1 + ky) + od.x;
            float px = (float)(pw[i] - 1 + kx) + od.y;
            float fy = floorf(py), fx = floorf(px);
            float wy = py - fy, wx = px - fx;
            int y0 = (int)fy, x0 = (int)fx;
            int y1 = y0 + 1, x1 = x0 + 1;
            bool vy0 = (unsigned)y0 < (unsigned)Hh, vy1 = (unsigned)y1 < (unsigned)Hh;
            bool vx0 = (unsigned)x0 < (unsigned)Ww, vx1 = (unsigned)x1 < (unsigned)Ww;
            int y0c = min(max(y0, 0), Hh - 1), y1c = min(max(y1, 0), Hh - 1);
            int x0c = min(max(x0, 0), Ww - 1), x1c = min(max(x1, 0), Ww - 1);
            ww[i][0] = (vy0 && vx0) ? (1.f - wy) * (1.f - wx) : 0.f;
            ww[i][1] = (vy0 && vx1) ? (1.f - wy) * wx : 0.f;
            ww[i][2] = (vy1 && vx0) ? wy * (1.f - wx) : 0.f;
            ww[i][3] = (vy1 && vx1) ? wy * wx : 0.f;
            int r0 = (bbase + y0c * Ww) * Cc, r1 = (bbase + y1c * Ww) * Cc;
            gg[i][0] = *(const bf16x8*)(xt + r0 + x0c * Cc + cb8);
            gg[i][1] = *(const bf16x8*)(xt + r0 + x1c * Cc + cb8);
            gg[i][2] = *(const bf16x8*)(xt + r1 + x0c * Cc + cb8);
            gg[i][3] = *(const bf16x8*)(xt + r1 + x1c * Cc + cb8);
        }
    };
    issue(0, g, w4);
    #pragma unroll
    for (int k = 0; k < 9; ++k) {
        #pragma unroll
        for (int i = 0; i < 2; ++i) {
            bf16x8 v;
            #pragma unroll
            for (int j = 0; j < 8; ++j) {
                float s = (float)g[i][0][j] * w4[i][0] + (float)g[i][1][j] * w4[i][1]
                        + (float)g[i][2][j] * w4[i][2] + (float)g[i][3][j] * w4[i][3];
                v[j] = (bf16_t)s;
            }
            *(bf16x8*)&myS[(i * 8 + prow) * 72 + cb8] = v;
        }
        if (k < 8) issue(k + 1, g, w4);   // gather k+1 flies over MFMA of k
        #pragma unroll
        for (int s = 0; s < 2; ++s) {
            bf16x8 bfrag = *(bf16x8*)&myS[(lane & 15) * 72 + s * 32 + ((lane >> 4) & 3) * 8];
            int t = k * 2 + s;
            #pragma unroll
            for (int mt = 0; mt < 4; ++mt) {
                bf16x8 afrag = __builtin_nontemporal_load(&wtpd_v[(t * 4 + mt) * 64 + lane]);
                acc[mt] = __builtin_amdgcn_mfma_f32_16x16x32_bf16(afrag, bfrag, acc[mt], 0, 0, 0);
            }
        }
    }
    #pragma unroll
    for (int mt = 0; mt < 4; ++mt)
        #pragma unroll
        for (int r = 0; r < 4; ++r) {
            int o = mt * 16 + ((lane >> 4) & 3) * 4 + r;
            int pix = q * 16 + (lane & 15);
            out[(b * Oo + o) * HW + (h0 + (pix >> 3)) * Ww + w0 + (pix & 7)] = acc[mt][r];
        }
}

extern "C" void kernel_launch(void* const* d_in, const int* in_sizes, int n_in,
                              void* d_out, int out_size, void* d_ws, size_t ws_size,
                              hipStream_t stream) {
    const float* x  = (const float*)d_in[0];
    const float* ow = (const float*)d_in[1];
    const float* ob = (const float*)d_in[2];
    const float* cw = (const float*)d_in[3];
    const float* cb = (const float*)d_in[4];
    float* out = (float*)d_out;

    bf16_t* xt   = (bf16_t*)d_ws;
    bf16_t* wtpd = xt + XT_SZ;
    bf16_t* wtpo = wtpd + WTPD_SZ;

    xpose_prep<<<1179, 256, 0, stream>>>(x, cw, ow, xt, wtpd, wtpo);
    fused_dcn <<<1152, 256, 0, stream>>>(xt, wtpo, wtpd, ob, cb, out);
}

// Round 9
// 112.740 us; speedup vs baseline: 1.2198x; 1.2198x over previous
//
#include <hip/hip_runtime.h>

#define Bb 8
#define Cc 64
#define Oo 64
#define Hh 96
#define Ww 96
#define HW 9216
#define NOFF 18

typedef __bf16 bf16_t;
typedef __bf16 bf16x2 __attribute__((ext_vector_type(2)));
typedef __bf16 bf16x8 __attribute__((ext_vector_type(8)));
typedef float  f32x4  __attribute__((ext_vector_type(4)));

// ws layout:
//   xt   : Bb*HW*Cc  bf16     [b][hw][c]
//   wtpd : 18*4*64*8 bf16     deform weights, A-fragment order
//   wtpo : 18*2*64*8 bf16     offset-conv weights, A-fragment order
#define XT_SZ   (Bb*HW*Cc)
#define WTPD_SZ (18*4*64*8)
#define WTPO_SZ (18*2*64*8)

// ---------------- kernel 1: x transpose + weight prepack (one grid) ----------------
__global__ void xpose_prep(const float* __restrict__ x, const float* __restrict__ cw,
                           const float* __restrict__ ow, bf16_t* __restrict__ xt,
                           bf16_t* __restrict__ wtpd, bf16_t* __restrict__ wtpo) {
    __shared__ float tile[64][65];
    int bid = blockIdx.x;
    if (bid < 1152) {
        int b    = bid / 144;
        int t0   = (bid % 144) * 64;
        int lane = threadIdx.x & 63;
        int sub  = threadIdx.x >> 6;
        const float* xb = x + (size_t)b * Cc * HW;
        #pragma unroll
        for (int i = 0; i < 16; ++i) {
            int c = sub * 16 + i;
            tile[c][lane] = xb[c * HW + t0 + lane];
        }
        __syncthreads();
        bf16_t* xtb = xt + ((size_t)b * HW + t0) * Cc;
        int half = lane >> 5, cpair = lane & 31;
        #pragma unroll
        for (int i = 0; i < 8; ++i) {
            int hw = sub * 16 + half * 8 + i;
            bf16x2 v;
            v[0] = (bf16_t)tile[cpair * 2][hw];
            v[1] = (bf16_t)tile[cpair * 2 + 1][hw];
            *(bf16x2*)&xtb[hw * Cc + cpair * 2] = v;
        }
    } else if (bid < 1170) {
        int n = (bid - 1152) * 256 + threadIdx.x;    // 0..4607
        int t = n >> 8; int rem = n & 255; int mt = rem >> 6; int l = rem & 63;
        int o = mt * 16 + (l & 15);
        int kbase = t * 32 + ((l >> 4) & 3) * 8;
        bf16x8 v;
        #pragma unroll
        for (int j = 0; j < 8; ++j) {
            int kidx = kbase + j; int k = kidx >> 6; int c = kidx & 63;
            v[j] = (bf16_t)cw[(o * 64 + c) * 9 + k];
        }
        *(bf16x8*)&wtpd[n * 8] = v;
    } else {
        int n = (bid - 1170) * 256 + threadIdx.x;    // 0..2303
        int t = n >> 7; int rem = n & 127; int mt = rem >> 6; int l = rem & 63;
        int oc = mt * 16 + (l & 15);
        int kbase = t * 32 + ((l >> 4) & 3) * 8;
        bf16x8 v;
        #pragma unroll
        for (int j = 0; j < 8; ++j) {
            int kidx = kbase + j; int k = kidx >> 6; int c = kidx & 63;
            v[j] = (oc < NOFF) ? (bf16_t)ow[(oc * 64 + c) * 9 + k] : (bf16_t)0.f;
        }
        *(bf16x8*)&wtpo[n * 8] = v;
    }
}

// ---------------- kernel 2: fused offset-conv + deformable conv ----------------
// XCD swizzle: b = bid&7 pins each XCD to one batch (L2-resident xt slice).
// 8x8 pixel tiles: per-block tap footprint ~13x13x128B = 21.6 KB < 32 KB L1.
// Weights: PLAIN loads (4 waves share the per-tap 8KB slab via L1 broadcast —
// nt loads defeated this and cost 10 us in r8) + register double-buffer so the
// weight fetch for tap k+1 flies over tap k's MFMAs.
__global__ __launch_bounds__(256, 3) void fused_dcn(const bf16_t* __restrict__ xt,
        const bf16_t* __restrict__ wtpo, const bf16_t* __restrict__ wtpd,
        const float* __restrict__ ob, const float* __restrict__ cb,
        float* __restrict__ out) {
    __shared__ float offbuf[64 * 20];            // [pix][18 pad 20]
    __shared__ bf16_t Sa[4][16 * 72];            // wave-private staging (both phases)

    int bid = blockIdx.x;
    int b = bid & 7;                              // XCD-aware remap
    int t8 = bid >> 3;                            // tile 0..143
    int h0 = (t8 / 12) * 8, w0 = (t8 % 12) * 8;   // 8x8 tile origin
    int tid = threadIdx.x, lane = tid & 63, q = tid >> 6;
    int cg = lane & 7, prow = lane >> 3;
    int cb8 = cg * 8;
    bf16_t* myS = &Sa[q][0];
    int bbase = b * HW;

    // wave q owns pixels q*16..q*16+15 = tile rows (q*2, q*2+1), cols 0..7
    int pl[2], ph[2], pw[2];
    #pragma unroll
    for (int i = 0; i < 2; ++i) {
        pl[i] = q * 16 + i * 8 + prow;            // pixel index in block
        ph[i] = h0 + q * 2 + i;                   // image row
        pw[i] = w0 + prow;                        // image col
    }

    const bf16x8* wtpo_v = (const bf16x8*)wtpo;
    const bf16x8* wtpd_v = (const bf16x8*)wtpd;

    // ---- phase 1: offset conv ----
    {
        f32x4 acc[2];
        #pragma unroll
        for (int mt = 0; mt < 2; ++mt)
            #pragma unroll
            for (int r = 0; r < 4; ++r) {
                int oc = mt * 16 + ((lane >> 4) & 3) * 4 + r;
                acc[mt][r] = (oc < NOFF) ? ob[oc] : 0.f;
            }
        bf16x8 g[2];
        bf16x8 wreg[2][2][2];       // [parity][s][mt]
        auto issue = [&](int k, bf16x8 (&gg)[2]) {
            const int ky = k / 3, kx = k % 3;
            #pragma unroll
            for (int i = 0; i < 2; ++i) {
                int y = ph[i] - 1 + ky, x = pw[i] - 1 + kx;
                bool valid = (y >= 0) && (y < Hh) && (x >= 0) && (x < Ww);
                bf16x8 v;
                #pragma unroll
                for (int j = 0; j < 8; ++j) v[j] = (bf16_t)0.f;
                if (valid) v = *(const bf16x8*)(xt + ((bbase + y * Ww + x) * Cc + cb8));
                gg[i] = v;
            }
        };
        auto loadw = [&](int k, bf16x8 (&w)[2][2]) {
            #pragma unroll
            for (int s = 0; s < 2; ++s)
                #pragma unroll
                for (int mt = 0; mt < 2; ++mt)
                    w[s][mt] = wtpo_v[((k * 2 + s) * 2 + mt) * 64 + lane];
        };
        issue(0, g);
        loadw(0, wreg[0]);
        #pragma unroll
        for (int k = 0; k < 9; ++k) {
            #pragma unroll
            for (int i = 0; i < 2; ++i)
                *(bf16x8*)&myS[(i * 8 + prow) * 72 + cb8] = g[i];   // pure bf16 copy
            if (k < 8) { issue(k + 1, g); loadw(k + 1, wreg[(k + 1) & 1]); }
            #pragma unroll
            for (int s = 0; s < 2; ++s) {
                bf16x8 bfrag = *(bf16x8*)&myS[(lane & 15) * 72 + s * 32 + ((lane >> 4) & 3) * 8];
                #pragma unroll
                for (int mt = 0; mt < 2; ++mt)
                    acc[mt] = __builtin_amdgcn_mfma_f32_16x16x32_bf16(wreg[k & 1][s][mt], bfrag, acc[mt], 0, 0, 0);
            }
        }
        // C-layout -> [pix][18] LDS (the transform deform needs anyway)
        #pragma unroll
        for (int mt = 0; mt < 2; ++mt)
            #pragma unroll
            for (int r = 0; r < 4; ++r) {
                int oc = mt * 16 + ((lane >> 4) & 3) * 4 + r;
                if (oc < NOFF)
                    offbuf[(q * 16 + (lane & 15)) * 20 + oc] = acc[mt][r];
            }
    }
    __syncthreads();

    // ---- phase 2: deformable conv ----
    f32x4 acc[4];
    #pragma unroll
    for (int mt = 0; mt < 4; ++mt)
        #pragma unroll
        for (int r = 0; r < 4; ++r)
            acc[mt][r] = cb[mt * 16 + ((lane >> 4) & 3) * 4 + r];

    bf16x8 g[2][4];        // in-flight gather: [i][corner], 16 B each
    float w4[2][4];        // bilinear weights (validity-premultiplied)
    bf16x8 wreg[2][2][4];  // [parity][s][mt] weight fragments in flight
    auto issue = [&](int k, bf16x8 (&gg)[2][4], float (&ww)[2][4]) {
        const int ky = k / 3, kx = k % 3;
        #pragma unroll
        for (int i = 0; i < 2; ++i) {
            float2 od = *(float2*)&offbuf[pl[i] * 20 + 2 * k];
            float py = (float)(ph[i] - 1 + ky) + od.x;
            float px = (float)(pw[i] - 1 + kx) + od.y;
            float fy = floorf(py), fx = floorf(px);
            float wy = py - fy, wx = px - fx;
            int y0 = (int)fy, x0 = (int)fx;
            int y1 = y0 + 1, x1 = x0 + 1;
            bool vy0 = (unsigned)y0 < (unsigned)Hh, vy1 = (unsigned)y1 < (unsigned)Hh;
            bool vx0 = (unsigned)x0 < (unsigned)Ww, vx1 = (unsigned)x1 < (unsigned)Ww;
            int y0c = min(max(y0, 0), Hh - 1), y1c = min(max(y1, 0), Hh - 1);
            int x0c = min(max(x0, 0), Ww - 1), x1c = min(max(x1, 0), Ww - 1);
            ww[i][0] = (vy0 && vx0) ? (1.f - wy) * (1.f - wx) : 0.f;
            ww[i][1] = (vy0 && vx1) ? (1.f - wy) * wx : 0.f;
            ww[i][2] = (vy1 && vx0) ? wy * (1.f - wx) : 0.f;
            ww[i][3] = (vy1 && vx1) ? wy * wx : 0.f;
            int r0 = (bbase + y0c * Ww) * Cc, r1 = (bbase + y1c * Ww) * Cc;
            gg[i][0] = *(const bf16x8*)(xt + r0 + x0c * Cc + cb8);
            gg[i][1] = *(const bf16x8*)(xt + r0 + x1c * Cc + cb8);
            gg[i][2] = *(const bf16x8*)(xt + r1 + x0c * Cc + cb8);
            gg[i][3] = *(const bf16x8*)(xt + r1 + x1c * Cc + cb8);
        }
    };
    auto loadw = [&](int k, bf16x8 (&w)[2][4]) {
        #pragma unroll
        for (int s = 0; s < 2; ++s)
            #pragma unroll
            for (int mt = 0; mt < 4; ++mt)
                w[s][mt] = wtpd_v[((k * 2 + s) * 4 + mt) * 64 + lane];
    };
    issue(0, g, w4);
    loadw(0, wreg[0]);
    #pragma unroll
    for (int k = 0; k < 9; ++k) {
        #pragma unroll
        for (int i = 0; i < 2; ++i) {
            bf16x8 v;
            #pragma unroll
            for (int j = 0; j < 8; ++j) {
                float s = (float)g[i][0][j] * w4[i][0] + (float)g[i][1][j] * w4[i][1]
                        + (float)g[i][2][j] * w4[i][2] + (float)g[i][3][j] * w4[i][3];
                v[j] = (bf16_t)s;
            }
            *(bf16x8*)&myS[(i * 8 + prow) * 72 + cb8] = v;
        }
        if (k < 8) { issue(k + 1, g, w4); loadw(k + 1, wreg[(k + 1) & 1]); }
        #pragma unroll
        for (int s = 0; s < 2; ++s) {
            bf16x8 bfrag = *(bf16x8*)&myS[(lane & 15) * 72 + s * 32 + ((lane >> 4) & 3) * 8];
            #pragma unroll
            for (int mt = 0; mt < 4; ++mt)
                acc[mt] = __builtin_amdgcn_mfma_f32_16x16x32_bf16(wreg[k & 1][s][mt], bfrag, acc[mt], 0, 0, 0);
        }
    }
    #pragma unroll
    for (int mt = 0; mt < 4; ++mt)
        #pragma unroll
        for (int r = 0; r < 4; ++r) {
            int o = mt * 16 + ((lane >> 4) & 3) * 4 + r;
            int pix = q * 16 + (lane & 15);
            out[(b * Oo + o) * HW + (h0 + (pix >> 3)) * Ww + w0 + (pix & 7)] = acc[mt][r];
        }
}

extern "C" void kernel_launch(void* const* d_in, const int* in_sizes, int n_in,
                              void* d_out, int out_size, void* d_ws, size_t ws_size,
                              hipStream_t stream) {
    const float* x  = (const float*)d_in[0];
    const float* ow = (const float*)d_in[1];
    const float* ob = (const float*)d_in[2];
    const float* cw = (const float*)d_in[3];
    const float* cb = (const float*)d_in[4];
    float* out = (float*)d_out;

    bf16_t* xt   = (bf16_t*)d_ws;
    bf16_t* wtpd = xt + XT_SZ;
    bf16_t* wtpo = wtpd + WTPD_SZ;

    xpose_prep<<<1179, 256, 0, stream>>>(x, cw, ow, xt, wtpd, wtpo);
    fused_dcn <<<1152, 256, 0, stream>>>(xt, wtpo, wtpd, ob, cb, out);
}